// Round 8
// baseline (168.342 us; speedup 1.0000x reference)
//
#include <hip/hip_runtime.h>

// z(8,128,64,64) f32, codes(16,256,8) f32
// out: soft(8,64,64,128) | hard(8,64,64,128) | idx(8,64,64,16) as f32
#define NPOS 32768
#define CCH  128
#define LL   16
#define KK   256
#define CD   8

typedef float f32x2 __attribute__((ext_vector_type(2)));

#if __has_builtin(__builtin_amdgcn_exp2f)
#define EXP2F(x) __builtin_amdgcn_exp2f(x)
#else
#define EXP2F(x) __builtin_exp2f(x)
#endif

// exp(-dist) = exp2(-sqrt(d2 * LOG2E^2)) : one v_mul per code (R6-proven)
#define LOG2E_SQ 2.0813689810056077f

// block: 256 threads = 1 latent x 256 positions (all 4 waves share one 8KB slice).
// grid latent-major: bid>>7 = latent, bid&127 = pos-chunk -> consecutive blocks
// share the codebook slice -> constant-cache hits instead of L2-latency s_loads.
// 2048 blocks = 8 blocks/CU = full 32-wave residency.
__global__ __launch_bounds__(256, 8) void soft_hard_enc(
    const float* __restrict__ z, const float* __restrict__ codes,
    float* __restrict__ out)
{
    const int tid = (int)threadIdx.x;
    const int bid = (int)blockIdx.x;
    const int l4      = bid >> 7;            // wave-uniform by construction
    const int posBase = (bid & 127) * 256;   // 256 | 4096: never straddles a batch
    const int pos = posBase + tid;
    const int b   = pos >> 12;
    const int wh  = pos & 4095;

    // hv: 8 channels raw, lane-coalesced per channel
    const float* zp = z + (((size_t)(b * CCH + l4 * CD)) << 12) + wh;
    float h0 = zp[0ull << 12], h1 = zp[1ull << 12], h2 = zp[2ull << 12], h3 = zp[3ull << 12];
    float h4 = zp[4ull << 12], h5 = zp[5ull << 12], h6 = zp[6ull << 12], h7 = zp[7ull << 12];
    // packed copies for the acc FMAs
    f32x2 hp01 = (f32x2){h0, h1}, hp23 = (f32x2){h2, h3};
    f32x2 hp45 = (f32x2){h4, h5}, hp67 = (f32x2){h6, h7};
    (void)hp01; (void)hp23; (void)hp45; (void)hp67;

    const float* __restrict__ cp = codes + (size_t)l4 * KK * CD;  // uniform slice

    f32x2 acc01 = (f32x2){0.f, 0.f}, acc23 = (f32x2){0.f, 0.f};
    f32x2 acc45 = (f32x2){0.f, 0.f}, acc67 = (f32x2){0.f, 0.f};
    float ssum = 0.0f;
    float bd   = 3.4e38f;
    int   bk   = 0;

#pragma unroll 4
    for (int k = 0; k < KK; ++k) {
        const float* ck = cp + k * CD;       // uniform -> s_load_dwordx16 per 2 codes
        float c0 = ck[0], c1 = ck[1], c2 = ck[2], c3 = ck[3];
        float c4 = ck[4], c5 = ck[5], c6 = ck[6], c7 = ck[7];

        // scalar d2 chain: 8 sub + 8 fma, no horizontal add (argmin-exact direct form)
        float d0 = h0 - c0, d1 = h1 - c1, d2c = h2 - c2, d3 = h3 - c3;
        float d4 = h4 - c4, d5 = h5 - c5, d6 = h6 - c6, d7 = h7 - c7;
        float d2 = d0 * d0;
        d2 = fmaf(d1, d1, d2);
        d2 = fmaf(d2c, d2c, d2);
        d2 = fmaf(d3, d3, d2);
        d2 = fmaf(d4, d4, d2);
        d2 = fmaf(d5, d5, d2);
        d2 = fmaf(d6, d6, d2);
        d2 = fmaf(d7, d7, d2);

        float s = __builtin_amdgcn_sqrtf(d2 * LOG2E_SQ);
        float e = EXP2F(-s);
        ssum += e;

        f32x2 ep = (f32x2){e, e};            // packed acc: 4x v_pk_fma
        acc01 = __builtin_elementwise_fma(ep, (f32x2){c0, c1}, acc01);
        acc23 = __builtin_elementwise_fma(ep, (f32x2){c2, c3}, acc23);
        acc45 = __builtin_elementwise_fma(ep, (f32x2){c4, c5}, acc45);
        acc67 = __builtin_elementwise_fma(ep, (f32x2){c6, c7}, acc67);

        if (d2 < bd) { bd = d2; bk = k; }    // strict < = np.argmin first occurrence
    }

    const float sc = 1.0f / ssum;

    const size_t obase = (size_t)pos * CCH + (size_t)(l4 * CD);
    *(float4*)&out[obase] =
        (float4){acc01[0] * sc, acc01[1] * sc, acc23[0] * sc, acc23[1] * sc};
    *(float4*)&out[obase + 4] =
        (float4){acc45[0] * sc, acc45[1] * sc, acc67[0] * sc, acc67[1] * sc};

    // hard: per-lane gather from L2-hot codes
    const float* hq = codes + ((size_t)(l4 * KK + bk)) * CD;
    float4 g0 = *(const float4*)(hq);
    float4 g1 = *(const float4*)(hq + 4);
    float* outh = out + (size_t)NPOS * CCH;
    *(float4*)&outh[obase]     = g0;
    *(float4*)&outh[obase + 4] = g1;

    float* outi = out + (size_t)2 * NPOS * CCH;
    outi[(size_t)pos * LL + l4] = (float)bk;
}

extern "C" void kernel_launch(void* const* d_in, const int* in_sizes, int n_in,
                              void* d_out, int out_size, void* d_ws, size_t ws_size,
                              hipStream_t stream) {
    const float* z     = (const float*)d_in[0];
    const float* codes = (const float*)d_in[1];
    float* out = (float*)d_out;
    soft_hard_enc<<<dim3(2048), dim3(256), 0, stream>>>(z, codes, out);
}